// Round 1
// baseline (1889.293 us; speedup 1.0000x reference)
//
#include <hip/hip_runtime.h>

constexpr int D = 128;

// Phase 1: scatter-add inputs[src[e]] into out[dst[e]].
// 32 threads per edge; each thread moves one float4 (16B) => 512B/edge coalesced gather.
__global__ __launch_bounds__(256) void scatter_kernel(
    const float* __restrict__ inputs,
    const int* __restrict__ src,
    const int* __restrict__ dst,
    float* __restrict__ out,
    long long total_threads)
{
    long long tid = (long long)blockIdx.x * blockDim.x + threadIdx.x;
    if (tid >= total_threads) return;
    int e = (int)(tid >> 5);
    int lane = (int)(tid & 31);
    int s = src[e];
    int dnode = dst[e];
    const float4 v = *(const float4*)(inputs + (size_t)s * D + lane * 4);
    float* op = out + (size_t)dnode * D + lane * 4;
    atomicAdd(op + 0, v.x);
    atomicAdd(op + 1, v.y);
    atomicAdd(op + 2, v.z);
    atomicAdd(op + 3, v.w);
}

// Phase 2: in-place per-node transform: out[n,:] = (out[n,:]/deg[n]) @ W + b
// W staged in LDS (64KB). 256 threads, 8 nodes per iteration.
// Thread (half, d): half = tid>>7 (0/1), d = tid&127. Each thread computes
// rows {half*4 .. half*4+3} at column d -> each Ws read feeds 4 FMAs.
__global__ __launch_bounds__(256) void transform_kernel(
    float* __restrict__ out,
    const float* __restrict__ degree,
    const float* __restrict__ W,
    const float* __restrict__ b,
    int N)
{
    __shared__ float Ws[D * D];      // 64 KB
    __shared__ float hs[8][D];       // 4 KB

    const int tid = threadIdx.x;
    for (int idx = tid; idx < D * D; idx += 256)
        Ws[idx] = W[idx];

    const int d    = tid & (D - 1);
    const int half = tid >> 7;          // 0 or 1
    const float bias = b[d];

    // loader mapping: row r = tid>>5 (0..7), cols c4..c4+3
    const int r  = tid >> 5;
    const int c4 = (tid & 31) * 4;

    __syncthreads();

    for (long long n0 = (long long)blockIdx.x * 8; n0 < N;
         n0 += (long long)gridDim.x * 8) {
        // load 8 rows of h, scaled by 1/deg
        {
            long long n = n0 + r;
            if (n < N) {
                const float invd = 1.0f / degree[n];
                const float4 v = *(const float4*)(out + (size_t)n * D + c4);
                hs[r][c4 + 0] = v.x * invd;
                hs[r][c4 + 1] = v.y * invd;
                hs[r][c4 + 2] = v.z * invd;
                hs[r][c4 + 3] = v.w * invd;
            } else {
                hs[r][c4 + 0] = 0.f;
                hs[r][c4 + 1] = 0.f;
                hs[r][c4 + 2] = 0.f;
                hs[r][c4 + 3] = 0.f;
            }
        }
        __syncthreads();

        float acc0 = bias, acc1 = bias, acc2 = bias, acc3 = bias;
        const int rb = half * 4;
        #pragma unroll
        for (int k = 0; k < D; ++k) {
            const float w = Ws[k * D + d];
            acc0 = fmaf(hs[rb + 0][k], w, acc0);
            acc1 = fmaf(hs[rb + 1][k], w, acc1);
            acc2 = fmaf(hs[rb + 2][k], w, acc2);
            acc3 = fmaf(hs[rb + 3][k], w, acc3);
        }

        // write back (rows were fully consumed into regs)
        const long long nb = n0 + rb;
        if (nb + 0 < N) out[(size_t)(nb + 0) * D + d] = acc0;
        if (nb + 1 < N) out[(size_t)(nb + 1) * D + d] = acc1;
        if (nb + 2 < N) out[(size_t)(nb + 2) * D + d] = acc2;
        if (nb + 3 < N) out[(size_t)(nb + 3) * D + d] = acc3;

        __syncthreads();   // protect hs before next iteration's reload
    }
}

extern "C" void kernel_launch(void* const* d_in, const int* in_sizes, int n_in,
                              void* d_out, int out_size, void* d_ws, size_t ws_size,
                              hipStream_t stream) {
    const float* inputs = (const float*)d_in[0];
    const int*   src    = (const int*)d_in[1];
    const int*   dst    = (const int*)d_in[2];
    const float* degree = (const float*)d_in[3];
    const float* W      = (const float*)d_in[4];
    const float* b      = (const float*)d_in[5];
    float* out = (float*)d_out;

    const int E = in_sizes[1];
    const int N = in_sizes[3];

    // zero the accumulator (d_out is poisoned / stale between calls)
    hipMemsetAsync(d_out, 0, (size_t)N * D * sizeof(float), stream);

    // scatter-add
    const long long total = (long long)E * 32;
    const int blocks = (int)((total + 255) / 256);
    scatter_kernel<<<blocks, 256, 0, stream>>>(inputs, src, dst, out, total);

    // in-place degree-normalize + linear
    transform_kernel<<<2048, 256, 0, stream>>>(out, degree, W, b, N);
}

// Round 2
// 1344.990 us; speedup vs baseline: 1.4047x; 1.4047x over previous
//
#include <hip/hip_runtime.h>

constexpr int D = 128;

// ---------------- CSR-build pipeline ----------------

__global__ __launch_bounds__(256) void hist_kernel(
    const int* __restrict__ dst, int* __restrict__ counts, int E)
{
    int e = blockIdx.x * 256 + threadIdx.x;
    if (e < E) atomicAdd(&counts[dst[e]], 1);
}

// per-block partial sums of counts (256 elems/block)
__global__ __launch_bounds__(256) void scan_partial_kernel(
    const int* __restrict__ counts, int* __restrict__ bsum, int N)
{
    __shared__ int a[256];
    int i = blockIdx.x * 256 + threadIdx.x;
    a[threadIdx.x] = (i < N) ? counts[i] : 0;
    __syncthreads();
    for (int off = 128; off > 0; off >>= 1) {
        if (threadIdx.x < off) a[threadIdx.x] += a[threadIdx.x + off];
        __syncthreads();
    }
    if (threadIdx.x == 0) bsum[blockIdx.x] = a[0];
}

// single-block exclusive scan of block sums (nscan <= 512)
__global__ __launch_bounds__(512) void scan_bsum_kernel(int* bsum, int nscan)
{
    __shared__ int a[512], b[512];
    int t = threadIdx.x;
    int v = (t < nscan) ? bsum[t] : 0;
    a[t] = v;
    __syncthreads();
    int* cur = a; int* nxt = b;
    for (int off = 1; off < 512; off <<= 1) {
        int x = cur[t];
        if (t >= off) x += cur[t - off];
        nxt[t] = x;
        __syncthreads();
        int* tmp = cur; cur = nxt; nxt = tmp;
    }
    if (t < nscan) bsum[t] = cur[t] - v;   // exclusive
}

// offsets[i] = exclusive scan of counts
__global__ __launch_bounds__(256) void scan_offsets_kernel(
    const int* __restrict__ counts, const int* __restrict__ bsum,
    int* __restrict__ offsets, int N)
{
    __shared__ int a[256], b[256];
    int i = blockIdx.x * 256 + threadIdx.x;
    int t = threadIdx.x;
    int v = (i < N) ? counts[i] : 0;
    a[t] = v;
    __syncthreads();
    int* cur = a; int* nxt = b;
    for (int off = 1; off < 256; off <<= 1) {
        int x = cur[t];
        if (t >= off) x += cur[t - off];
        nxt[t] = x;
        __syncthreads();
        int* tmp = cur; cur = nxt; nxt = tmp;
    }
    if (i < N) offsets[i] = bsum[blockIdx.x] + cur[t] - v;
}

// bucket scatter: destructively bumps offsets; afterwards offsets[n] = bucket END
__global__ __launch_bounds__(256) void bucket_kernel(
    const int* __restrict__ src, const int* __restrict__ dst,
    int* __restrict__ offsets, int* __restrict__ edge_src, int E)
{
    int e = blockIdx.x * 256 + threadIdx.x;
    if (e < E) {
        int pos = atomicAdd(&offsets[dst[e]], 1);
        edge_src[pos] = src[e];
    }
}

// one wave per node: sum incoming src rows, scale by 1/deg, write h to out
__global__ __launch_bounds__(256) void aggregate_kernel(
    const float* __restrict__ inputs, const int* __restrict__ edge_src,
    const int* __restrict__ counts, const int* __restrict__ offsets_end,
    const float* __restrict__ degree, float* __restrict__ out, int N)
{
    const int wid = threadIdx.x >> 6;
    const int lane = threadIdx.x & 63;
    const long long n = (long long)blockIdx.x * 4 + wid;
    if (n >= N) return;
    const int end = offsets_end[n];
    const int cnt = counts[n];
    const int beg = end - cnt;
    const int c = lane * 2;
    float ax = 0.f, ay = 0.f;
    int i = beg;
    for (; i + 1 < end; i += 2) {
        int s0 = edge_src[i];
        int s1 = edge_src[i + 1];
        const float2 v0 = *(const float2*)(inputs + (size_t)s0 * D + c);
        const float2 v1 = *(const float2*)(inputs + (size_t)s1 * D + c);
        ax += v0.x + v1.x;
        ay += v0.y + v1.y;
    }
    if (i < end) {
        int s0 = edge_src[i];
        const float2 v0 = *(const float2*)(inputs + (size_t)s0 * D + c);
        ax += v0.x;
        ay += v0.y;
    }
    const float invd = 1.0f / degree[n];
    float2 r; r.x = ax * invd; r.y = ay * invd;
    *(float2*)(out + (size_t)n * D + c) = r;
}

// ---------------- transform: out = h @ W + b (h already normalized, in-place) ----------------
// 256 threads; thread (g, cp): g = tid>>6 (8-row group), cp = tid&63 (col pair).
// 32 nodes/block-iter staged in LDS. Per k-step-4: 8 broadcast b128 hs reads + 4 b64 Ws reads
// feed 64 FMAs.
__global__ __launch_bounds__(256) void transform2_kernel(
    float* __restrict__ out, const float* __restrict__ W,
    const float* __restrict__ b, int N)
{
    __shared__ float Ws[D * D];       // 64 KB
    __shared__ float hs[32][D];       // 16 KB

    const int tid = threadIdx.x;
    for (int i = tid; i < D * D; i += 256) Ws[i] = W[i];

    const int cp = tid & 63;
    const int g  = tid >> 6;
    const int c0 = cp * 2;
    float2 bias; bias.x = b[c0]; bias.y = b[c0 + 1];

    const int lr = tid >> 3;          // loader row 0..31
    const int lq = (tid & 7) * 16;    // loader col start

    __syncthreads();

    for (long long n0 = (long long)blockIdx.x * 32; n0 < N;
         n0 += (long long)gridDim.x * 32) {
        const long long ln = n0 + lr;
        #pragma unroll
        for (int j = 0; j < 16; j += 4) {
            float4 v = (ln < N) ? *(const float4*)(out + ln * D + lq + j)
                                : make_float4(0.f, 0.f, 0.f, 0.f);
            *(float4*)&hs[lr][lq + j] = v;
        }
        __syncthreads();

        float2 acc[8];
        #pragma unroll
        for (int r = 0; r < 8; ++r) acc[r] = bias;
        const int rb = g * 8;

        for (int k = 0; k < D; k += 4) {
            float4 hv[8];
            #pragma unroll
            for (int r = 0; r < 8; ++r) hv[r] = *(const float4*)&hs[rb + r][k];
            #pragma unroll
            for (int kk = 0; kk < 4; ++kk) {
                const float2 w = *(const float2*)&Ws[(k + kk) * D + c0];
                #pragma unroll
                for (int r = 0; r < 8; ++r) {
                    const float h = (kk == 0) ? hv[r].x : (kk == 1) ? hv[r].y
                                  : (kk == 2) ? hv[r].z : hv[r].w;
                    acc[r].x = fmaf(h, w.x, acc[r].x);
                    acc[r].y = fmaf(h, w.y, acc[r].y);
                }
            }
        }
        __syncthreads();   // hs fully consumed

        #pragma unroll
        for (int r = 0; r < 8; ++r) {
            const long long n = n0 + rb + r;
            if (n < N) *(float2*)(out + n * D + c0) = acc[r];
        }
    }
}

// ---------------- fallback (atomic) path ----------------

__global__ __launch_bounds__(256) void scatter_kernel(
    const float* __restrict__ inputs, const int* __restrict__ src,
    const int* __restrict__ dst, float* __restrict__ out, long long total_threads)
{
    long long tid = (long long)blockIdx.x * blockDim.x + threadIdx.x;
    if (tid >= total_threads) return;
    int e = (int)(tid >> 5);
    int lane = (int)(tid & 31);
    const float4 v = *(const float4*)(inputs + (size_t)src[e] * D + lane * 4);
    float* op = out + (size_t)dst[e] * D + lane * 4;
    atomicAdd(op + 0, v.x);
    atomicAdd(op + 1, v.y);
    atomicAdd(op + 2, v.z);
    atomicAdd(op + 3, v.w);
}

__global__ __launch_bounds__(256) void divide_kernel(
    float* __restrict__ out, const float* __restrict__ degree, int N)
{
    long long i = (long long)blockIdx.x * 256 + threadIdx.x;
    if (i < (long long)N * D) {
        out[i] /= degree[i >> 7];
    }
}

extern "C" void kernel_launch(void* const* d_in, const int* in_sizes, int n_in,
                              void* d_out, int out_size, void* d_ws, size_t ws_size,
                              hipStream_t stream) {
    const float* inputs = (const float*)d_in[0];
    const int*   src    = (const int*)d_in[1];
    const int*   dst    = (const int*)d_in[2];
    const float* degree = (const float*)d_in[3];
    const float* W      = (const float*)d_in[4];
    const float* b      = (const float*)d_in[5];
    float* out = (float*)d_out;

    const int E = in_sizes[1];
    const int N = in_sizes[3];
    const int nscan = (N + 255) / 256;

    const size_t needed = ((size_t)2 * N + 512 + (size_t)E) * sizeof(int);

    if (ws_size >= needed && nscan <= 512) {
        int* counts   = (int*)d_ws;
        int* offsets  = counts + N;
        int* bsum     = offsets + N;
        int* edge_src = bsum + 512;

        hipMemsetAsync(counts, 0, (size_t)N * sizeof(int), stream);
        hist_kernel<<<(E + 255) / 256, 256, 0, stream>>>(dst, counts, E);
        scan_partial_kernel<<<nscan, 256, 0, stream>>>(counts, bsum, N);
        scan_bsum_kernel<<<1, 512, 0, stream>>>(bsum, nscan);
        scan_offsets_kernel<<<nscan, 256, 0, stream>>>(counts, bsum, offsets, N);
        bucket_kernel<<<(E + 255) / 256, 256, 0, stream>>>(src, dst, offsets, edge_src, E);
        aggregate_kernel<<<(N + 3) / 4, 256, 0, stream>>>(
            inputs, edge_src, counts, offsets, degree, out, N);
    } else {
        hipMemsetAsync(d_out, 0, (size_t)N * D * sizeof(float), stream);
        const long long total = (long long)E * 32;
        scatter_kernel<<<(int)((total + 255) / 256), 256, 0, stream>>>(inputs, src, dst, out, total);
        divide_kernel<<<(int)(((long long)N * D + 255) / 256), 256, 0, stream>>>(out, degree, N);
    }

    transform2_kernel<<<(N + 31) / 32, 256, 0, stream>>>(out, W, b, N);
}

// Round 3
// 204.230 us; speedup vs baseline: 9.2508x; 6.5857x over previous
//
#include <hip/hip_runtime.h>

constexpr int D = 128;

// ---------------- CSR-build pipeline ----------------

__global__ __launch_bounds__(256) void hist_kernel(
    const int* __restrict__ dst, int* __restrict__ counts, int E)
{
    int e = blockIdx.x * 256 + threadIdx.x;
    if (e < E) atomicAdd(&counts[dst[e]], 1);
}

__global__ __launch_bounds__(256) void scan_partial_kernel(
    const int* __restrict__ counts, int* __restrict__ bsum, int N)
{
    __shared__ int a[256];
    int i = blockIdx.x * 256 + threadIdx.x;
    a[threadIdx.x] = (i < N) ? counts[i] : 0;
    __syncthreads();
    for (int off = 128; off > 0; off >>= 1) {
        if (threadIdx.x < off) a[threadIdx.x] += a[threadIdx.x + off];
        __syncthreads();
    }
    if (threadIdx.x == 0) bsum[blockIdx.x] = a[0];
}

__global__ __launch_bounds__(512) void scan_bsum_kernel(int* bsum, int nscan)
{
    __shared__ int a[512], b[512];
    int t = threadIdx.x;
    int v = (t < nscan) ? bsum[t] : 0;
    a[t] = v;
    __syncthreads();
    int* cur = a; int* nxt = b;
    for (int off = 1; off < 512; off <<= 1) {
        int x = cur[t];
        if (t >= off) x += cur[t - off];
        nxt[t] = x;
        __syncthreads();
        int* tmp = cur; cur = nxt; nxt = tmp;
    }
    if (t < nscan) bsum[t] = cur[t] - v;   // exclusive
}

__global__ __launch_bounds__(256) void scan_offsets_kernel(
    const int* __restrict__ counts, const int* __restrict__ bsum,
    int* __restrict__ offsets, int N)
{
    __shared__ int a[256], b[256];
    int i = blockIdx.x * 256 + threadIdx.x;
    int t = threadIdx.x;
    int v = (i < N) ? counts[i] : 0;
    a[t] = v;
    __syncthreads();
    int* cur = a; int* nxt = b;
    for (int off = 1; off < 256; off <<= 1) {
        int x = cur[t];
        if (t >= off) x += cur[t - off];
        nxt[t] = x;
        __syncthreads();
        int* tmp = cur; cur = nxt; nxt = tmp;
    }
    if (i < N) offsets[i] = bsum[blockIdx.x] + cur[t] - v;
}

// bucket scatter: destructively bumps offsets; afterwards offsets[n] = bucket END
__global__ __launch_bounds__(256) void bucket_kernel(
    const int* __restrict__ src, const int* __restrict__ dst,
    int* __restrict__ offsets, int* __restrict__ edge_src, int E)
{
    int e = blockIdx.x * 256 + threadIdx.x;
    if (e < E) {
        int pos = atomicAdd(&offsets[dst[e]], 1);
        edge_src[pos] = src[e];
    }
}

// one wave per node: sum incoming src rows, scale by 1/deg, write h to out
__global__ __launch_bounds__(256) void aggregate_kernel(
    const float* __restrict__ inputs, const int* __restrict__ edge_src,
    const int* __restrict__ counts, const int* __restrict__ offsets_end,
    const float* __restrict__ degree, float* __restrict__ out, int N)
{
    const int wid = threadIdx.x >> 6;
    const int lane = threadIdx.x & 63;
    const long long n = (long long)blockIdx.x * 4 + wid;
    if (n >= N) return;
    const int end = offsets_end[n];
    const int cnt = counts[n];
    const int beg = end - cnt;
    const int c = lane * 2;
    float ax = 0.f, ay = 0.f;
    int i = beg;
    for (; i + 1 < end; i += 2) {
        int s0 = edge_src[i];
        int s1 = edge_src[i + 1];
        const float2 v0 = *(const float2*)(inputs + (size_t)s0 * D + c);
        const float2 v1 = *(const float2*)(inputs + (size_t)s1 * D + c);
        ax += v0.x + v1.x;
        ay += v0.y + v1.y;
    }
    if (i < end) {
        int s0 = edge_src[i];
        const float2 v0 = *(const float2*)(inputs + (size_t)s0 * D + c);
        ax += v0.x;
        ay += v0.y;
    }
    const float invd = 1.0f / degree[n];
    float2 r; r.x = ax * invd; r.y = ay * invd;
    *(float2*)(out + (size_t)n * D + c) = r;
}

// ---------------- transform: out = h @ W + b (in-place, h pre-normalized) ----
// Spill-proof shape: 256 threads, 16-node LDS tile.
// Thread (g, cp): cp = tid&63 -> column pair c0 = cp*2; g = tid>>6 -> rows g*4..g*4+3.
// acc = 8 VGPR, h-frags = 16 VGPR. Per 32 FMAs: 4 broadcast ds_read_b128 (free)
// + 4 ds_read_b64 (2-way, free). #pragma unroll 2 caps live range;
// __launch_bounds__(256,4) caps VGPR at 128 (round-2 kernel hit 256 + 3.8GB spill).
__global__ __launch_bounds__(256, 4) void transform3_kernel(
    float* __restrict__ out, const float* __restrict__ W,
    const float* __restrict__ b, int N)
{
    __shared__ float Ws[D * D];          // 64 KB
    __shared__ float hs[16][D + 4];      // 8.25 KB, +4 pad keeps 16B align, breaks write conflicts

    const int tid = threadIdx.x;
    for (int i = tid; i < D * D; i += 256) Ws[i] = W[i];

    const int c0 = (tid & 63) * 2;
    const int rb = (tid >> 6) * 4;
    float2 bias; bias.x = b[c0]; bias.y = b[c0 + 1];

    const int lr = tid >> 4;             // loader row 0..15
    const int lc = (tid & 15) * 8;       // loader col start

    __syncthreads();                     // Ws ready

    for (int n0 = blockIdx.x * 16; n0 < N; n0 += gridDim.x * 16) {
        const int ln = n0 + lr;
        if (ln < N) {
            const float4 v0 = *(const float4*)(out + (size_t)ln * D + lc);
            const float4 v1 = *(const float4*)(out + (size_t)ln * D + lc + 4);
            *(float4*)&hs[lr][lc]     = v0;
            *(float4*)&hs[lr][lc + 4] = v1;
        } else {
            const float4 z = make_float4(0.f, 0.f, 0.f, 0.f);
            *(float4*)&hs[lr][lc]     = z;
            *(float4*)&hs[lr][lc + 4] = z;
        }
        __syncthreads();

        float2 acc0 = bias, acc1 = bias, acc2 = bias, acc3 = bias;

        #pragma unroll 2
        for (int k = 0; k < D; k += 4) {
            const float4 h0 = *(const float4*)&hs[rb + 0][k];
            const float4 h1 = *(const float4*)&hs[rb + 1][k];
            const float4 h2 = *(const float4*)&hs[rb + 2][k];
            const float4 h3 = *(const float4*)&hs[rb + 3][k];
            #pragma unroll
            for (int kk = 0; kk < 4; ++kk) {
                const float2 w = *(const float2*)&Ws[(k + kk) * D + c0];
                const float e0 = (kk == 0) ? h0.x : (kk == 1) ? h0.y : (kk == 2) ? h0.z : h0.w;
                const float e1 = (kk == 0) ? h1.x : (kk == 1) ? h1.y : (kk == 2) ? h1.z : h1.w;
                const float e2 = (kk == 0) ? h2.x : (kk == 1) ? h2.y : (kk == 2) ? h2.z : h2.w;
                const float e3 = (kk == 0) ? h3.x : (kk == 1) ? h3.y : (kk == 2) ? h3.z : h3.w;
                acc0.x = fmaf(e0, w.x, acc0.x); acc0.y = fmaf(e0, w.y, acc0.y);
                acc1.x = fmaf(e1, w.x, acc1.x); acc1.y = fmaf(e1, w.y, acc1.y);
                acc2.x = fmaf(e2, w.x, acc2.x); acc2.y = fmaf(e2, w.y, acc2.y);
                acc3.x = fmaf(e3, w.x, acc3.x); acc3.y = fmaf(e3, w.y, acc3.y);
            }
        }
        __syncthreads();                 // hs fully consumed before next reload

        const int nb = n0 + rb;
        if (nb + 0 < N) *(float2*)(out + (size_t)(nb + 0) * D + c0) = acc0;
        if (nb + 1 < N) *(float2*)(out + (size_t)(nb + 1) * D + c0) = acc1;
        if (nb + 2 < N) *(float2*)(out + (size_t)(nb + 2) * D + c0) = acc2;
        if (nb + 3 < N) *(float2*)(out + (size_t)(nb + 3) * D + c0) = acc3;
    }
}

// ---------------- fallback (atomic) path ----------------

__global__ __launch_bounds__(256) void scatter_kernel(
    const float* __restrict__ inputs, const int* __restrict__ src,
    const int* __restrict__ dst, float* __restrict__ out, long long total_threads)
{
    long long tid = (long long)blockIdx.x * blockDim.x + threadIdx.x;
    if (tid >= total_threads) return;
    int e = (int)(tid >> 5);
    int lane = (int)(tid & 31);
    const float4 v = *(const float4*)(inputs + (size_t)src[e] * D + lane * 4);
    float* op = out + (size_t)dst[e] * D + lane * 4;
    atomicAdd(op + 0, v.x);
    atomicAdd(op + 1, v.y);
    atomicAdd(op + 2, v.z);
    atomicAdd(op + 3, v.w);
}

__global__ __launch_bounds__(256) void divide_kernel(
    float* __restrict__ out, const float* __restrict__ degree, int N)
{
    long long i = (long long)blockIdx.x * 256 + threadIdx.x;
    if (i < (long long)N * D) {
        out[i] /= degree[i >> 7];
    }
}

extern "C" void kernel_launch(void* const* d_in, const int* in_sizes, int n_in,
                              void* d_out, int out_size, void* d_ws, size_t ws_size,
                              hipStream_t stream) {
    const float* inputs = (const float*)d_in[0];
    const int*   src    = (const int*)d_in[1];
    const int*   dst    = (const int*)d_in[2];
    const float* degree = (const float*)d_in[3];
    const float* W      = (const float*)d_in[4];
    const float* b      = (const float*)d_in[5];
    float* out = (float*)d_out;

    const int E = in_sizes[1];
    const int N = in_sizes[3];
    const int nscan = (N + 255) / 256;

    const size_t needed = ((size_t)2 * N + 512 + (size_t)E) * sizeof(int);

    if (ws_size >= needed && nscan <= 512) {
        int* counts   = (int*)d_ws;
        int* offsets  = counts + N;
        int* bsum     = offsets + N;
        int* edge_src = bsum + 512;

        hipMemsetAsync(counts, 0, (size_t)N * sizeof(int), stream);
        hist_kernel<<<(E + 255) / 256, 256, 0, stream>>>(dst, counts, E);
        scan_partial_kernel<<<nscan, 256, 0, stream>>>(counts, bsum, N);
        scan_bsum_kernel<<<1, 512, 0, stream>>>(bsum, nscan);
        scan_offsets_kernel<<<nscan, 256, 0, stream>>>(counts, bsum, offsets, N);
        bucket_kernel<<<(E + 255) / 256, 256, 0, stream>>>(src, dst, offsets, edge_src, E);
        aggregate_kernel<<<(N + 3) / 4, 256, 0, stream>>>(
            inputs, edge_src, counts, offsets, degree, out, N);
    } else {
        hipMemsetAsync(d_out, 0, (size_t)N * D * sizeof(float), stream);
        const long long total = (long long)E * 32;
        scatter_kernel<<<(int)((total + 255) / 256), 256, 0, stream>>>(inputs, src, dst, out, total);
        divide_kernel<<<(int)(((long long)N * D + 255) / 256), 256, 0, stream>>>(out, degree, N);
    }

    transform3_kernel<<<2048, 256, 0, stream>>>(out, W, b, N);
}

// Round 4
// 123.959 us; speedup vs baseline: 15.2413x; 1.6476x over previous
//
#include <hip/hip_runtime.h>

constexpr int D = 128;

using short8 = __attribute__((ext_vector_type(8))) short;
using f32x4  = __attribute__((ext_vector_type(4))) float;

__device__ inline unsigned short f2bf(float f) {
    unsigned u = __float_as_uint(f);
    u = (u + 0x7FFFu + ((u >> 16) & 1u)) >> 16;   // RN-even
    return (unsigned short)u;
}

// ---------------- CSR-build (counts derived from degree; no hist) ----------------

__global__ __launch_bounds__(256) void scan_partial_kernel(
    const float* __restrict__ degree, int* __restrict__ bsum, int N)
{
    __shared__ int a[256];
    int i = blockIdx.x * 256 + threadIdx.x;
    a[threadIdx.x] = (i < N) ? (int)degree[i] : 0;
    __syncthreads();
    for (int off = 128; off > 0; off >>= 1) {
        if (threadIdx.x < off) a[threadIdx.x] += a[threadIdx.x + off];
        __syncthreads();
    }
    if (threadIdx.x == 0) bsum[blockIdx.x] = a[0];
}

__global__ __launch_bounds__(512) void scan_bsum_kernel(int* bsum, int nscan)
{
    __shared__ int a[512], b[512];
    int t = threadIdx.x;
    int v = (t < nscan) ? bsum[t] : 0;
    a[t] = v;
    __syncthreads();
    int* cur = a; int* nxt = b;
    for (int off = 1; off < 512; off <<= 1) {
        int x = cur[t];
        if (t >= off) x += cur[t - off];
        nxt[t] = x;
        __syncthreads();
        int* tmp = cur; cur = nxt; nxt = tmp;
    }
    if (t < nscan) bsum[t] = cur[t] - v;   // exclusive
}

// starts[i] = exclusive scan of (int)degree; work[i] = same (bucket bumps work)
__global__ __launch_bounds__(256) void scan_offsets_kernel(
    const float* __restrict__ degree, const int* __restrict__ bsum,
    int* __restrict__ starts, int* __restrict__ work, int N)
{
    __shared__ int a[256], b[256];
    int i = blockIdx.x * 256 + threadIdx.x;
    int t = threadIdx.x;
    int v = (i < N) ? (int)degree[i] : 0;
    a[t] = v;
    __syncthreads();
    int* cur = a; int* nxt = b;
    for (int off = 1; off < 256; off <<= 1) {
        int x = cur[t];
        if (t >= off) x += cur[t - off];
        nxt[t] = x;
        __syncthreads();
        int* tmp = cur; cur = nxt; nxt = tmp;
    }
    if (i < N) {
        int val = bsum[blockIdx.x] + cur[t] - v;
        starts[i] = val;
        work[i]   = val;
    }
}

__global__ __launch_bounds__(256) void bucket_kernel(
    const int* __restrict__ src, const int* __restrict__ dst,
    int* __restrict__ work, int* __restrict__ edge_src, int E)
{
    int e = blockIdx.x * 256 + threadIdx.x;
    if (e < E) {
        int pos = atomicAdd(&work[dst[e]], 1);
        edge_src[pos] = src[e];
    }
}

// one wave per node: sum incoming rows, scale by 1/deg, write bf16 h
__global__ __launch_bounds__(256) void aggregate_bf16_kernel(
    const float* __restrict__ inputs, const int* __restrict__ edge_src,
    const int* __restrict__ starts, const int* __restrict__ work,
    const float* __restrict__ degree, unsigned short* __restrict__ h, int N)
{
    const int wid = threadIdx.x >> 6;
    const int lane = threadIdx.x & 63;
    const int n = blockIdx.x * 4 + wid;
    if (n >= N) return;
    const int beg = starts[n];
    const int end = work[n];
    const int c = lane * 2;
    float ax = 0.f, ay = 0.f;
    int i = beg;
    for (; i + 1 < end; i += 2) {
        int s0 = edge_src[i];
        int s1 = edge_src[i + 1];
        const float2 v0 = *(const float2*)(inputs + (size_t)s0 * D + c);
        const float2 v1 = *(const float2*)(inputs + (size_t)s1 * D + c);
        ax += v0.x + v1.x;
        ay += v0.y + v1.y;
    }
    if (i < end) {
        const float2 v0 = *(const float2*)(inputs + (size_t)edge_src[i] * D + c);
        ax += v0.x;
        ay += v0.y;
    }
    const float invd = 1.0f / degree[n];
    unsigned hx = f2bf(ax * invd);
    unsigned hy = f2bf(ay * invd);
    *(unsigned*)(h + (size_t)n * D + c) = hx | (hy << 16);
}

// ---------------- transform: out = h(bf16) @ W + b via MFMA ----------------
// 512 threads = 8 waves. wave -> (wr = w>>1 row sub-tile, wc = w&1 col half).
// Block iter = 64 rows x 128 cols. B-frags (4 col-tiles x 4 k-steps, 64 VGPR)
// built once per block from an LDS fp32 copy of W; A-frags straight from global
// (16 rows x 64B contiguous per instr). No LDS in the main loop.
// 16x16x32 layouts: A row=l&15, k=(l>>4)*8+j ; B col=l&15, k=(l>>4)*8+j ;
// D col=l&15, row=(l>>4)*4+q   [guide §3, m89/m91-verified]
__global__ __launch_bounds__(512) void transform_mfma_kernel(
    const unsigned short* __restrict__ h, const float* __restrict__ W,
    const float* __restrict__ b, float* __restrict__ out, int N)
{
    __shared__ float Wlds[D * D];        // 64 KB, used only for frag build
    const int tid = threadIdx.x;
    for (int i = tid; i < D * D / 4; i += 512)
        ((float4*)Wlds)[i] = ((const float4*)W)[i];
    __syncthreads();

    const int l    = tid & 63;
    const int wave = tid >> 6;
    const int wr   = wave >> 1;          // 0..3
    const int wc   = wave & 1;           // 0..1
    const int lcol = l & 15;
    const int lk   = (l >> 4) * 8;

    short8 Bf[4][4];
    float  bias[4];
    #pragma unroll
    for (int c = 0; c < 4; ++c) {
        const int col = wc * 64 + c * 16 + lcol;
        bias[c] = b[col];
        #pragma unroll
        for (int ks = 0; ks < 4; ++ks) {
            #pragma unroll
            for (int j = 0; j < 8; ++j)
                Bf[c][ks][j] = (short)f2bf(Wlds[(ks * 32 + lk + j) * D + col]);
        }
    }

    const short8 zero = {0, 0, 0, 0, 0, 0, 0, 0};

    for (int r0 = blockIdx.x * 64 + wr * 16; r0 < N; r0 += gridDim.x * 64) {
        const int arow = r0 + lcol;
        short8 Af[4];
        if (arow < N) {
            #pragma unroll
            for (int ks = 0; ks < 4; ++ks)
                Af[ks] = *(const short8*)(h + (size_t)arow * D + ks * 32 + lk);
        } else {
            #pragma unroll
            for (int ks = 0; ks < 4; ++ks) Af[ks] = zero;
        }

        #pragma unroll
        for (int c = 0; c < 4; ++c) {
            f32x4 acc = {bias[c], bias[c], bias[c], bias[c]};
            #pragma unroll
            for (int ks = 0; ks < 4; ++ks)
                acc = __builtin_amdgcn_mfma_f32_16x16x32_bf16(Af[ks], Bf[c][ks], acc, 0, 0, 0);
            const int col = wc * 64 + c * 16 + lcol;
            #pragma unroll
            for (int q = 0; q < 4; ++q) {
                const int row = r0 + (l >> 4) * 4 + q;
                if (row < N) out[(size_t)row * D + col] = acc[q];
            }
        }
    }
}

// ---------------- mid path (fp32 h in d_out) ----------------

__global__ __launch_bounds__(256) void aggregate_f32_kernel(
    const float* __restrict__ inputs, const int* __restrict__ edge_src,
    const int* __restrict__ starts, const int* __restrict__ work,
    const float* __restrict__ degree, float* __restrict__ out, int N)
{
    const int wid = threadIdx.x >> 6;
    const int lane = threadIdx.x & 63;
    const int n = blockIdx.x * 4 + wid;
    if (n >= N) return;
    const int beg = starts[n];
    const int end = work[n];
    const int c = lane * 2;
    float ax = 0.f, ay = 0.f;
    for (int i = beg; i < end; ++i) {
        const float2 v = *(const float2*)(inputs + (size_t)edge_src[i] * D + c);
        ax += v.x;
        ay += v.y;
    }
    const float invd = 1.0f / degree[n];
    float2 r; r.x = ax * invd; r.y = ay * invd;
    *(float2*)(out + (size_t)n * D + c) = r;
}

__global__ __launch_bounds__(256, 4) void transform3_kernel(
    float* __restrict__ out, const float* __restrict__ W,
    const float* __restrict__ b, int N)
{
    __shared__ float Ws[D * D];
    __shared__ float hs[16][D + 4];

    const int tid = threadIdx.x;
    for (int i = tid; i < D * D; i += 256) Ws[i] = W[i];

    const int c0 = (tid & 63) * 2;
    const int rb = (tid >> 6) * 4;
    float2 bias; bias.x = b[c0]; bias.y = b[c0 + 1];
    const int lr = tid >> 4;
    const int lc = (tid & 15) * 8;
    __syncthreads();

    for (int n0 = blockIdx.x * 16; n0 < N; n0 += gridDim.x * 16) {
        const int ln = n0 + lr;
        if (ln < N) {
            *(float4*)&hs[lr][lc]     = *(const float4*)(out + (size_t)ln * D + lc);
            *(float4*)&hs[lr][lc + 4] = *(const float4*)(out + (size_t)ln * D + lc + 4);
        } else {
            const float4 z = make_float4(0.f, 0.f, 0.f, 0.f);
            *(float4*)&hs[lr][lc] = z;
            *(float4*)&hs[lr][lc + 4] = z;
        }
        __syncthreads();

        float2 acc0 = bias, acc1 = bias, acc2 = bias, acc3 = bias;
        #pragma unroll 2
        for (int k = 0; k < D; k += 4) {
            const float4 h0 = *(const float4*)&hs[rb + 0][k];
            const float4 h1 = *(const float4*)&hs[rb + 1][k];
            const float4 h2 = *(const float4*)&hs[rb + 2][k];
            const float4 h3 = *(const float4*)&hs[rb + 3][k];
            #pragma unroll
            for (int kk = 0; kk < 4; ++kk) {
                const float2 w = *(const float2*)&Ws[(k + kk) * D + c0];
                const float e0 = (kk == 0) ? h0.x : (kk == 1) ? h0.y : (kk == 2) ? h0.z : h0.w;
                const float e1 = (kk == 0) ? h1.x : (kk == 1) ? h1.y : (kk == 2) ? h1.z : h1.w;
                const float e2 = (kk == 0) ? h2.x : (kk == 1) ? h2.y : (kk == 2) ? h2.z : h2.w;
                const float e3 = (kk == 0) ? h3.x : (kk == 1) ? h3.y : (kk == 2) ? h3.z : h3.w;
                acc0.x = fmaf(e0, w.x, acc0.x); acc0.y = fmaf(e0, w.y, acc0.y);
                acc1.x = fmaf(e1, w.x, acc1.x); acc1.y = fmaf(e1, w.y, acc1.y);
                acc2.x = fmaf(e2, w.x, acc2.x); acc2.y = fmaf(e2, w.y, acc2.y);
                acc3.x = fmaf(e3, w.x, acc3.x); acc3.y = fmaf(e3, w.y, acc3.y);
            }
        }
        __syncthreads();

        const int nb = n0 + rb;
        if (nb + 0 < N) *(float2*)(out + (size_t)(nb + 0) * D + c0) = acc0;
        if (nb + 1 < N) *(float2*)(out + (size_t)(nb + 1) * D + c0) = acc1;
        if (nb + 2 < N) *(float2*)(out + (size_t)(nb + 2) * D + c0) = acc2;
        if (nb + 3 < N) *(float2*)(out + (size_t)(nb + 3) * D + c0) = acc3;
    }
}

// ---------------- atomic fallback ----------------

__global__ __launch_bounds__(256) void scatter_kernel(
    const float* __restrict__ inputs, const int* __restrict__ src,
    const int* __restrict__ dst, float* __restrict__ out, long long total_threads)
{
    long long tid = (long long)blockIdx.x * blockDim.x + threadIdx.x;
    if (tid >= total_threads) return;
    int e = (int)(tid >> 5);
    int lane = (int)(tid & 31);
    const float4 v = *(const float4*)(inputs + (size_t)src[e] * D + lane * 4);
    float* op = out + (size_t)dst[e] * D + lane * 4;
    atomicAdd(op + 0, v.x);
    atomicAdd(op + 1, v.y);
    atomicAdd(op + 2, v.z);
    atomicAdd(op + 3, v.w);
}

__global__ __launch_bounds__(256) void divide_kernel(
    float* __restrict__ out, const float* __restrict__ degree, int N)
{
    long long i = (long long)blockIdx.x * 256 + threadIdx.x;
    if (i < (long long)N * D) out[i] /= degree[i >> 7];
}

extern "C" void kernel_launch(void* const* d_in, const int* in_sizes, int n_in,
                              void* d_out, int out_size, void* d_ws, size_t ws_size,
                              hipStream_t stream) {
    const float* inputs = (const float*)d_in[0];
    const int*   src    = (const int*)d_in[1];
    const int*   dst    = (const int*)d_in[2];
    const float* degree = (const float*)d_in[3];
    const float* W      = (const float*)d_in[4];
    const float* b      = (const float*)d_in[5];
    float* out = (float*)d_out;

    const int E = in_sizes[1];
    const int N = in_sizes[3];
    const int nscan = (N + 255) / 256;

    // ws layout: starts[N] | work[N] | bsum[512] | edge_src[E+N] | (align16) h_bf16[N*D]
    const size_t ints_csr  = (size_t)3 * N + 512 + E;        // through edge_src
    const size_t h_off     = ((ints_csr * 4) + 15) & ~(size_t)15;
    const size_t needed_full = h_off + (size_t)N * D * 2;
    const size_t needed_csr  = ints_csr * 4;

    if (ws_size >= needed_full && nscan <= 512) {
        int* starts   = (int*)d_ws;
        int* work     = starts + N;
        int* bsum     = work + N;
        int* edge_src = bsum + 512;
        unsigned short* hbf = (unsigned short*)((char*)d_ws + h_off);

        scan_partial_kernel<<<nscan, 256, 0, stream>>>(degree, bsum, N);
        scan_bsum_kernel<<<1, 512, 0, stream>>>(bsum, nscan);
        scan_offsets_kernel<<<nscan, 256, 0, stream>>>(degree, bsum, starts, work, N);
        bucket_kernel<<<(E + 255) / 256, 256, 0, stream>>>(src, dst, work, edge_src, E);
        aggregate_bf16_kernel<<<(N + 3) / 4, 256, 0, stream>>>(
            inputs, edge_src, starts, work, degree, hbf, N);
        transform_mfma_kernel<<<512, 512, 0, stream>>>(hbf, W, b, out, N);
    } else if (ws_size >= needed_csr && nscan <= 512) {
        int* starts   = (int*)d_ws;
        int* work     = starts + N;
        int* bsum     = work + N;
        int* edge_src = bsum + 512;

        scan_partial_kernel<<<nscan, 256, 0, stream>>>(degree, bsum, N);
        scan_bsum_kernel<<<1, 512, 0, stream>>>(bsum, nscan);
        scan_offsets_kernel<<<nscan, 256, 0, stream>>>(degree, bsum, starts, work, N);
        bucket_kernel<<<(E + 255) / 256, 256, 0, stream>>>(src, dst, work, edge_src, E);
        aggregate_f32_kernel<<<(N + 3) / 4, 256, 0, stream>>>(
            inputs, edge_src, starts, work, degree, out, N);
        transform3_kernel<<<2048, 256, 0, stream>>>(out, W, b, N);
    } else {
        hipMemsetAsync(d_out, 0, (size_t)N * D * sizeof(float), stream);
        const long long total = (long long)E * 32;
        scatter_kernel<<<(int)((total + 255) / 256), 256, 0, stream>>>(inputs, src, dst, out, total);
        divide_kernel<<<(int)(((long long)N * D + 255) / 256), 256, 0, stream>>>(out, degree, N);
        transform3_kernel<<<2048, 256, 0, stream>>>(out, W, b, N);
    }
}

// Round 5
// 120.111 us; speedup vs baseline: 15.7295x; 1.0320x over previous
//
#include <hip/hip_runtime.h>

constexpr int D = 128;

using short8 = __attribute__((ext_vector_type(8))) short;
using f32x4  = __attribute__((ext_vector_type(4))) float;

__device__ inline unsigned short f2bf(float f) {
    unsigned u = __float_as_uint(f);
    u = (u + 0x7FFFu + ((u >> 16) & 1u)) >> 16;   // RN-even
    return (unsigned short)u;
}
__device__ inline unsigned pack2bf(float a, float b) {
    return (unsigned)f2bf(a) | ((unsigned)f2bf(b) << 16);
}

// ---------------- cast inputs (fp32) -> xin (bf16), 8 elems/thread ----------------
__global__ __launch_bounds__(256) void cast_bf16_kernel(
    const float* __restrict__ in, unsigned short* __restrict__ xin, long long total8)
{
    long long i = (long long)blockIdx.x * 256 + threadIdx.x;
    if (i >= total8) return;
    const float4 a = *(const float4*)(in + i * 8);
    const float4 c = *(const float4*)(in + i * 8 + 4);
    uint4 o;
    o.x = pack2bf(a.x, a.y);
    o.y = pack2bf(a.z, a.w);
    o.z = pack2bf(c.x, c.y);
    o.w = pack2bf(c.z, c.w);
    *(uint4*)(xin + i * 8) = o;
}

// ---------------- CSR-build (counts derived from degree; no hist) ----------------

__global__ __launch_bounds__(256) void scan_partial_kernel(
    const float* __restrict__ degree, int* __restrict__ bsum, int N)
{
    __shared__ int a[256];
    int i = blockIdx.x * 256 + threadIdx.x;
    a[threadIdx.x] = (i < N) ? (int)degree[i] : 0;
    __syncthreads();
    for (int off = 128; off > 0; off >>= 1) {
        if (threadIdx.x < off) a[threadIdx.x] += a[threadIdx.x + off];
        __syncthreads();
    }
    if (threadIdx.x == 0) bsum[blockIdx.x] = a[0];
}

__global__ __launch_bounds__(512) void scan_bsum_kernel(int* bsum, int nscan)
{
    __shared__ int a[512], b[512];
    int t = threadIdx.x;
    int v = (t < nscan) ? bsum[t] : 0;
    a[t] = v;
    __syncthreads();
    int* cur = a; int* nxt = b;
    for (int off = 1; off < 512; off <<= 1) {
        int x = cur[t];
        if (t >= off) x += cur[t - off];
        nxt[t] = x;
        __syncthreads();
        int* tmp = cur; cur = nxt; nxt = tmp;
    }
    if (t < nscan) bsum[t] = cur[t] - v;   // exclusive
}

__global__ __launch_bounds__(256) void scan_offsets_kernel(
    const float* __restrict__ degree, const int* __restrict__ bsum,
    int* __restrict__ starts, int* __restrict__ work, int N)
{
    __shared__ int a[256], b[256];
    int i = blockIdx.x * 256 + threadIdx.x;
    int t = threadIdx.x;
    int v = (i < N) ? (int)degree[i] : 0;
    a[t] = v;
    __syncthreads();
    int* cur = a; int* nxt = b;
    for (int off = 1; off < 256; off <<= 1) {
        int x = cur[t];
        if (t >= off) x += cur[t - off];
        nxt[t] = x;
        __syncthreads();
        int* tmp = cur; cur = nxt; nxt = tmp;
    }
    if (i < N) {
        int val = bsum[blockIdx.x] + cur[t] - v;
        starts[i] = val;
        work[i]   = val;
    }
}

__global__ __launch_bounds__(256) void bucket_kernel(
    const int* __restrict__ src, const int* __restrict__ dst,
    int* __restrict__ work, int* __restrict__ edge_src, int E)
{
    int e = blockIdx.x * 256 + threadIdx.x;
    if (e < E) {
        int pos = atomicAdd(&work[dst[e]], 1);
        edge_src[pos] = src[e];
    }
}

// one wave per node: sum incoming bf16 rows (fp32 accum), scale by 1/deg, write bf16 h
__global__ __launch_bounds__(256) void aggregate_xbf_kernel(
    const unsigned short* __restrict__ xin, const int* __restrict__ edge_src,
    const int* __restrict__ starts, const int* __restrict__ work,
    const float* __restrict__ degree, unsigned short* __restrict__ h, int N)
{
    const int wid = threadIdx.x >> 6;
    const int lane = threadIdx.x & 63;
    const int n = blockIdx.x * 4 + wid;
    if (n >= N) return;
    const int beg = starts[n];
    const int end = work[n];
    const int c = lane * 2;
    float ax = 0.f, ay = 0.f;
    int i = beg;
    for (; i + 3 < end; i += 4) {
        const unsigned v0 = *(const unsigned*)(xin + (size_t)edge_src[i]     * D + c);
        const unsigned v1 = *(const unsigned*)(xin + (size_t)edge_src[i + 1] * D + c);
        const unsigned v2 = *(const unsigned*)(xin + (size_t)edge_src[i + 2] * D + c);
        const unsigned v3 = *(const unsigned*)(xin + (size_t)edge_src[i + 3] * D + c);
        ax += __uint_as_float(v0 << 16) + __uint_as_float(v1 << 16)
            + __uint_as_float(v2 << 16) + __uint_as_float(v3 << 16);
        ay += __uint_as_float(v0 & 0xFFFF0000u) + __uint_as_float(v1 & 0xFFFF0000u)
            + __uint_as_float(v2 & 0xFFFF0000u) + __uint_as_float(v3 & 0xFFFF0000u);
    }
    for (; i < end; ++i) {
        const unsigned v = *(const unsigned*)(xin + (size_t)edge_src[i] * D + c);
        ax += __uint_as_float(v << 16);
        ay += __uint_as_float(v & 0xFFFF0000u);
    }
    const float invd = 1.0f / degree[n];
    *(unsigned*)(h + (size_t)n * D + c) = pack2bf(ax * invd, ay * invd);
}

// ---------------- transform: out = h(bf16) @ W + b via MFMA ----------------
__global__ __launch_bounds__(512) void transform_mfma_kernel(
    const unsigned short* __restrict__ h, const float* __restrict__ W,
    const float* __restrict__ b, float* __restrict__ out, int N)
{
    __shared__ float Wlds[D * D];        // 64 KB, used only for frag build
    const int tid = threadIdx.x;
    for (int i = tid; i < D * D / 4; i += 512)
        ((float4*)Wlds)[i] = ((const float4*)W)[i];
    __syncthreads();

    const int l    = tid & 63;
    const int wave = tid >> 6;
    const int wr   = wave >> 1;          // 0..3
    const int wc   = wave & 1;           // 0..1
    const int lcol = l & 15;
    const int lk   = (l >> 4) * 8;

    short8 Bf[4][4];
    float  bias[4];
    #pragma unroll
    for (int c = 0; c < 4; ++c) {
        const int col = wc * 64 + c * 16 + lcol;
        bias[c] = b[col];
        #pragma unroll
        for (int ks = 0; ks < 4; ++ks) {
            #pragma unroll
            for (int j = 0; j < 8; ++j)
                Bf[c][ks][j] = (short)f2bf(Wlds[(ks * 32 + lk + j) * D + col]);
        }
    }

    const short8 zero = {0, 0, 0, 0, 0, 0, 0, 0};

    for (int r0 = blockIdx.x * 64 + wr * 16; r0 < N; r0 += gridDim.x * 64) {
        const int arow = r0 + lcol;
        short8 Af[4];
        if (arow < N) {
            #pragma unroll
            for (int ks = 0; ks < 4; ++ks)
                Af[ks] = *(const short8*)(h + (size_t)arow * D + ks * 32 + lk);
        } else {
            #pragma unroll
            for (int ks = 0; ks < 4; ++ks) Af[ks] = zero;
        }

        #pragma unroll
        for (int c = 0; c < 4; ++c) {
            f32x4 acc = {bias[c], bias[c], bias[c], bias[c]};
            #pragma unroll
            for (int ks = 0; ks < 4; ++ks)
                acc = __builtin_amdgcn_mfma_f32_16x16x32_bf16(Af[ks], Bf[c][ks], acc, 0, 0, 0);
            const int col = wc * 64 + c * 16 + lcol;
            #pragma unroll
            for (int q = 0; q < 4; ++q) {
                const int row = r0 + (l >> 4) * 4 + q;
                if (row < N) out[(size_t)row * D + col] = acc[q];
            }
        }
    }
}

// ---------------- mid path (fp32 h in d_out) ----------------

__global__ __launch_bounds__(256) void aggregate_f32_kernel(
    const float* __restrict__ inputs, const int* __restrict__ edge_src,
    const int* __restrict__ starts, const int* __restrict__ work,
    const float* __restrict__ degree, float* __restrict__ out, int N)
{
    const int wid = threadIdx.x >> 6;
    const int lane = threadIdx.x & 63;
    const int n = blockIdx.x * 4 + wid;
    if (n >= N) return;
    const int beg = starts[n];
    const int end = work[n];
    const int c = lane * 2;
    float ax = 0.f, ay = 0.f;
    for (int i = beg; i < end; ++i) {
        const float2 v = *(const float2*)(inputs + (size_t)edge_src[i] * D + c);
        ax += v.x;
        ay += v.y;
    }
    const float invd = 1.0f / degree[n];
    float2 r; r.x = ax * invd; r.y = ay * invd;
    *(float2*)(out + (size_t)n * D + c) = r;
}

__global__ __launch_bounds__(256, 4) void transform3_kernel(
    float* __restrict__ out, const float* __restrict__ W,
    const float* __restrict__ b, int N)
{
    __shared__ float Ws[D * D];
    __shared__ float hs[16][D + 4];

    const int tid = threadIdx.x;
    for (int i = tid; i < D * D; i += 256) Ws[i] = W[i];

    const int c0 = (tid & 63) * 2;
    const int rb = (tid >> 6) * 4;
    float2 bias; bias.x = b[c0]; bias.y = b[c0 + 1];
    const int lr = tid >> 4;
    const int lc = (tid & 15) * 8;
    __syncthreads();

    for (int n0 = blockIdx.x * 16; n0 < N; n0 += gridDim.x * 16) {
        const int ln = n0 + lr;
        if (ln < N) {
            *(float4*)&hs[lr][lc]     = *(const float4*)(out + (size_t)ln * D + lc);
            *(float4*)&hs[lr][lc + 4] = *(const float4*)(out + (size_t)ln * D + lc + 4);
        } else {
            const float4 z = make_float4(0.f, 0.f, 0.f, 0.f);
            *(float4*)&hs[lr][lc] = z;
            *(float4*)&hs[lr][lc + 4] = z;
        }
        __syncthreads();

        float2 acc0 = bias, acc1 = bias, acc2 = bias, acc3 = bias;
        #pragma unroll 2
        for (int k = 0; k < D; k += 4) {
            const float4 h0 = *(const float4*)&hs[rb + 0][k];
            const float4 h1 = *(const float4*)&hs[rb + 1][k];
            const float4 h2 = *(const float4*)&hs[rb + 2][k];
            const float4 h3 = *(const float4*)&hs[rb + 3][k];
            #pragma unroll
            for (int kk = 0; kk < 4; ++kk) {
                const float2 w = *(const float2*)&Ws[(k + kk) * D + c0];
                const float e0 = (kk == 0) ? h0.x : (kk == 1) ? h0.y : (kk == 2) ? h0.z : h0.w;
                const float e1 = (kk == 0) ? h1.x : (kk == 1) ? h1.y : (kk == 2) ? h1.z : h1.w;
                const float e2 = (kk == 0) ? h2.x : (kk == 1) ? h2.y : (kk == 2) ? h2.z : h2.w;
                const float e3 = (kk == 0) ? h3.x : (kk == 1) ? h3.y : (kk == 2) ? h3.z : h3.w;
                acc0.x = fmaf(e0, w.x, acc0.x); acc0.y = fmaf(e0, w.y, acc0.y);
                acc1.x = fmaf(e1, w.x, acc1.x); acc1.y = fmaf(e1, w.y, acc1.y);
                acc2.x = fmaf(e2, w.x, acc2.x); acc2.y = fmaf(e2, w.y, acc2.y);
                acc3.x = fmaf(e3, w.x, acc3.x); acc3.y = fmaf(e3, w.y, acc3.y);
            }
        }
        __syncthreads();

        const int nb = n0 + rb;
        if (nb + 0 < N) *(float2*)(out + (size_t)(nb + 0) * D + c0) = acc0;
        if (nb + 1 < N) *(float2*)(out + (size_t)(nb + 1) * D + c0) = acc1;
        if (nb + 2 < N) *(float2*)(out + (size_t)(nb + 2) * D + c0) = acc2;
        if (nb + 3 < N) *(float2*)(out + (size_t)(nb + 3) * D + c0) = acc3;
    }
}

// ---------------- atomic fallback ----------------

__global__ __launch_bounds__(256) void scatter_kernel(
    const float* __restrict__ inputs, const int* __restrict__ src,
    const int* __restrict__ dst, float* __restrict__ out, long long total_threads)
{
    long long tid = (long long)blockIdx.x * blockDim.x + threadIdx.x;
    if (tid >= total_threads) return;
    int e = (int)(tid >> 5);
    int lane = (int)(tid & 31);
    const float4 v = *(const float4*)(inputs + (size_t)src[e] * D + lane * 4);
    float* op = out + (size_t)dst[e] * D + lane * 4;
    atomicAdd(op + 0, v.x);
    atomicAdd(op + 1, v.y);
    atomicAdd(op + 2, v.z);
    atomicAdd(op + 3, v.w);
}

__global__ __launch_bounds__(256) void divide_kernel(
    float* __restrict__ out, const float* __restrict__ degree, int N)
{
    long long i = (long long)blockIdx.x * 256 + threadIdx.x;
    if (i < (long long)N * D) out[i] /= degree[i >> 7];
}

extern "C" void kernel_launch(void* const* d_in, const int* in_sizes, int n_in,
                              void* d_out, int out_size, void* d_ws, size_t ws_size,
                              hipStream_t stream) {
    const float* inputs = (const float*)d_in[0];
    const int*   src    = (const int*)d_in[1];
    const int*   dst    = (const int*)d_in[2];
    const float* degree = (const float*)d_in[3];
    const float* W      = (const float*)d_in[4];
    const float* b      = (const float*)d_in[5];
    float* out = (float*)d_out;

    const int E = in_sizes[1];
    const int N = in_sizes[3];
    const int nscan = (N + 255) / 256;

    // ws layout: starts[N] | work[N] | bsum[512] | edge_src[E+N] | (align16) h_bf16[N*D]
    // xin (bf16 copy of inputs) lives in d_out's first 25.6 MB — dead until transform writes.
    const size_t ints_csr  = (size_t)3 * N + 512 + E;
    const size_t h_off     = ((ints_csr * 4) + 15) & ~(size_t)15;
    const size_t needed_full = h_off + (size_t)N * D * 2;
    const size_t needed_csr  = ints_csr * 4;

    if (ws_size >= needed_full && nscan <= 512) {
        int* starts   = (int*)d_ws;
        int* work     = starts + N;
        int* bsum     = work + N;
        int* edge_src = bsum + 512;
        unsigned short* hbf = (unsigned short*)((char*)d_ws + h_off);
        unsigned short* xin = (unsigned short*)d_out;   // scratch alias, freed by stream order

        const long long total8 = (long long)N * D / 8;
        cast_bf16_kernel<<<(int)((total8 + 255) / 256), 256, 0, stream>>>(inputs, xin, total8);
        scan_partial_kernel<<<nscan, 256, 0, stream>>>(degree, bsum, N);
        scan_bsum_kernel<<<1, 512, 0, stream>>>(bsum, nscan);
        scan_offsets_kernel<<<nscan, 256, 0, stream>>>(degree, bsum, starts, work, N);
        bucket_kernel<<<(E + 255) / 256, 256, 0, stream>>>(src, dst, work, edge_src, E);
        aggregate_xbf_kernel<<<(N + 3) / 4, 256, 0, stream>>>(
            xin, edge_src, starts, work, degree, hbf, N);
        transform_mfma_kernel<<<512, 512, 0, stream>>>(hbf, W, b, out, N);
    } else if (ws_size >= needed_csr && nscan <= 512) {
        int* starts   = (int*)d_ws;
        int* work     = starts + N;
        int* bsum     = work + N;
        int* edge_src = bsum + 512;

        scan_partial_kernel<<<nscan, 256, 0, stream>>>(degree, bsum, N);
        scan_bsum_kernel<<<1, 512, 0, stream>>>(bsum, nscan);
        scan_offsets_kernel<<<nscan, 256, 0, stream>>>(degree, bsum, starts, work, N);
        bucket_kernel<<<(E + 255) / 256, 256, 0, stream>>>(src, dst, work, edge_src, E);
        aggregate_f32_kernel<<<(N + 3) / 4, 256, 0, stream>>>(
            inputs, edge_src, starts, work, degree, out, N);
        transform3_kernel<<<2048, 256, 0, stream>>>(out, W, b, N);
    } else {
        hipMemsetAsync(d_out, 0, (size_t)N * D * sizeof(float), stream);
        const long long total = (long long)E * 32;
        scatter_kernel<<<(int)((total + 255) / 256), 256, 0, stream>>>(inputs, src, dst, out, total);
        divide_kernel<<<(int)(((long long)N * D + 255) / 256), 256, 0, stream>>>(out, degree, N);
        transform3_kernel<<<2048, 256, 0, stream>>>(out, W, b, N);
    }
}

// Round 6
// 116.190 us; speedup vs baseline: 16.2603x; 1.0337x over previous
//
#include <hip/hip_runtime.h>

constexpr int D = 128;

using short8 = __attribute__((ext_vector_type(8))) short;
using f32x4  = __attribute__((ext_vector_type(4))) float;

__device__ inline unsigned short f2bf(float f) {
    unsigned u = __float_as_uint(f);
    u = (u + 0x7FFFu + ((u >> 16) & 1u)) >> 16;   // RN-even
    return (unsigned short)u;
}
__device__ inline unsigned pack2bf(float a, float b) {
    return (unsigned)f2bf(a) | ((unsigned)f2bf(b) << 16);
}

// ---------------- cast inputs (fp32) -> xin (bf16), 8 elems/thread ----------------
__global__ __launch_bounds__(256) void cast_bf16_kernel(
    const float* __restrict__ in, unsigned short* __restrict__ xin, long long total8)
{
    long long i = (long long)blockIdx.x * 256 + threadIdx.x;
    if (i >= total8) return;
    const float4 a = *(const float4*)(in + i * 8);
    const float4 c = *(const float4*)(in + i * 8 + 4);
    uint4 o;
    o.x = pack2bf(a.x, a.y);
    o.y = pack2bf(a.z, a.w);
    o.z = pack2bf(c.x, c.y);
    o.w = pack2bf(c.z, c.w);
    *(uint4*)(xin + i * 8) = o;
}

// ---------------- CSR-build (counts derived from degree; no hist) ----------------

__global__ __launch_bounds__(256) void scan_partial_kernel(
    const float* __restrict__ degree, int* __restrict__ bsum, int N)
{
    __shared__ int a[256];
    int i = blockIdx.x * 256 + threadIdx.x;
    a[threadIdx.x] = (i < N) ? (int)degree[i] : 0;
    __syncthreads();
    for (int off = 128; off > 0; off >>= 1) {
        if (threadIdx.x < off) a[threadIdx.x] += a[threadIdx.x + off];
        __syncthreads();
    }
    if (threadIdx.x == 0) bsum[blockIdx.x] = a[0];
}

// offsets with inline prefix over bsum (saves the separate bsum-scan launch)
__global__ __launch_bounds__(256) void scan_offsets_kernel(
    const float* __restrict__ degree, const int* __restrict__ bsum,
    int* __restrict__ starts, int* __restrict__ work, int N)
{
    __shared__ int a[256], b2[256];
    __shared__ int prefix_s;
    const int t = threadIdx.x;
    const int i = blockIdx.x * 256 + t;

    // prefix = sum of bsum[0 .. blockIdx.x)
    int p = 0;
    for (int j = t; j < blockIdx.x; j += 256) p += bsum[j];
    a[t] = p;
    __syncthreads();
    for (int off = 128; off > 0; off >>= 1) {
        if (t < off) a[t] += a[t + off];
        __syncthreads();
    }
    if (t == 0) prefix_s = a[0];
    __syncthreads();
    const int prefix = prefix_s;
    __syncthreads();

    // local inclusive scan of this block's 256 counts
    const int v = (i < N) ? (int)degree[i] : 0;
    a[t] = v;
    __syncthreads();
    int* cur = a; int* nxt = b2;
    for (int off = 1; off < 256; off <<= 1) {
        int x = cur[t];
        if (t >= off) x += cur[t - off];
        nxt[t] = x;
        __syncthreads();
        int* tmp = cur; cur = nxt; nxt = tmp;
    }
    if (i < N) {
        const int val = prefix + cur[t] - v;   // exclusive
        starts[i] = val;
        work[i]   = val;
    }
}

__global__ __launch_bounds__(256) void bucket_kernel(
    const int* __restrict__ src, const int* __restrict__ dst,
    int* __restrict__ work, int* __restrict__ edge_src, int E)
{
    int e = blockIdx.x * 256 + threadIdx.x;
    if (e < E) {
        int pos = atomicAdd(&work[dst[e]], 1);
        edge_src[pos] = src[e];
    }
}

// one wave per node; 16 lanes per row (uint4 = 8 bf16), 4 edge slots per wave.
// One wave-load gathers 4 edges (1 KB). Cross-slot reduce via shfl_xor(16,32).
__global__ __launch_bounds__(256) void aggregate_xbf4_kernel(
    const unsigned short* __restrict__ xin, const int* __restrict__ edge_src,
    const int* __restrict__ starts, const int* __restrict__ work,
    const float* __restrict__ degree, unsigned short* __restrict__ h, int N)
{
    const int wid  = threadIdx.x >> 6;
    const int lane = threadIdx.x & 63;
    const int n = blockIdx.x * 4 + wid;
    if (n >= N) return;
    const int beg = starts[n];
    const int end = work[n];
    const int g = lane >> 4;            // edge slot 0..3
    const int t = lane & 15;            // col group: cols t*8 .. t*8+7
    const size_t coff = (size_t)t * 8;

    float ax[8];
    #pragma unroll
    for (int k = 0; k < 8; ++k) ax[k] = 0.f;

    #pragma unroll 2
    for (int i = beg; i < end; i += 4) {
        const int ii = i + g;
        if (ii < end) {
            const int s = edge_src[ii];
            const uint4 v = *(const uint4*)(xin + (size_t)s * D + coff);
            ax[0] += __uint_as_float(v.x << 16);
            ax[1] += __uint_as_float(v.x & 0xFFFF0000u);
            ax[2] += __uint_as_float(v.y << 16);
            ax[3] += __uint_as_float(v.y & 0xFFFF0000u);
            ax[4] += __uint_as_float(v.z << 16);
            ax[5] += __uint_as_float(v.z & 0xFFFF0000u);
            ax[6] += __uint_as_float(v.w << 16);
            ax[7] += __uint_as_float(v.w & 0xFFFF0000u);
        }
    }

    #pragma unroll
    for (int k = 0; k < 8; ++k) {
        ax[k] += __shfl_xor(ax[k], 16, 64);
        ax[k] += __shfl_xor(ax[k], 32, 64);
    }

    if (g == 0) {
        const float invd = 1.0f / degree[n];
        uint4 o;
        o.x = pack2bf(ax[0] * invd, ax[1] * invd);
        o.y = pack2bf(ax[2] * invd, ax[3] * invd);
        o.z = pack2bf(ax[4] * invd, ax[5] * invd);
        o.w = pack2bf(ax[6] * invd, ax[7] * invd);
        *(uint4*)(h + (size_t)n * D + coff) = o;
    }
}

// ---------------- transform: out = h(bf16) @ W + b via MFMA ----------------
__global__ __launch_bounds__(512) void transform_mfma_kernel(
    const unsigned short* __restrict__ h, const float* __restrict__ W,
    const float* __restrict__ b, float* __restrict__ out, int N)
{
    __shared__ float Wlds[D * D];        // 64 KB, used only for frag build
    const int tid = threadIdx.x;
    for (int i = tid; i < D * D / 4; i += 512)
        ((float4*)Wlds)[i] = ((const float4*)W)[i];
    __syncthreads();

    const int l    = tid & 63;
    const int wave = tid >> 6;
    const int wr   = wave >> 1;          // 0..3
    const int wc   = wave & 1;           // 0..1
    const int lcol = l & 15;
    const int lk   = (l >> 4) * 8;

    short8 Bf[4][4];
    float  bias[4];
    #pragma unroll
    for (int c = 0; c < 4; ++c) {
        const int col = wc * 64 + c * 16 + lcol;
        bias[c] = b[col];
        #pragma unroll
        for (int ks = 0; ks < 4; ++ks) {
            #pragma unroll
            for (int j = 0; j < 8; ++j)
                Bf[c][ks][j] = (short)f2bf(Wlds[(ks * 32 + lk + j) * D + col]);
        }
    }

    const short8 zero = {0, 0, 0, 0, 0, 0, 0, 0};

    for (int r0 = blockIdx.x * 64 + wr * 16; r0 < N; r0 += gridDim.x * 64) {
        const int arow = r0 + lcol;
        short8 Af[4];
        if (arow < N) {
            #pragma unroll
            for (int ks = 0; ks < 4; ++ks)
                Af[ks] = *(const short8*)(h + (size_t)arow * D + ks * 32 + lk);
        } else {
            #pragma unroll
            for (int ks = 0; ks < 4; ++ks) Af[ks] = zero;
        }

        #pragma unroll
        for (int c = 0; c < 4; ++c) {
            f32x4 acc = {bias[c], bias[c], bias[c], bias[c]};
            #pragma unroll
            for (int ks = 0; ks < 4; ++ks)
                acc = __builtin_amdgcn_mfma_f32_16x16x32_bf16(Af[ks], Bf[c][ks], acc, 0, 0, 0);
            const int col = wc * 64 + c * 16 + lcol;
            #pragma unroll
            for (int q = 0; q < 4; ++q) {
                const int row = r0 + (l >> 4) * 4 + q;
                if (row < N) out[(size_t)row * D + col] = acc[q];
            }
        }
    }
}

// ---------------- mid path (fp32 h in d_out) ----------------

__global__ __launch_bounds__(256) void aggregate_f32_kernel(
    const float* __restrict__ inputs, const int* __restrict__ edge_src,
    const int* __restrict__ starts, const int* __restrict__ work,
    const float* __restrict__ degree, float* __restrict__ out, int N)
{
    const int wid = threadIdx.x >> 6;
    const int lane = threadIdx.x & 63;
    const int n = blockIdx.x * 4 + wid;
    if (n >= N) return;
    const int beg = starts[n];
    const int end = work[n];
    const int c = lane * 2;
    float ax = 0.f, ay = 0.f;
    for (int i = beg; i < end; ++i) {
        const float2 v = *(const float2*)(inputs + (size_t)edge_src[i] * D + c);
        ax += v.x;
        ay += v.y;
    }
    const float invd = 1.0f / degree[n];
    float2 r; r.x = ax * invd; r.y = ay * invd;
    *(float2*)(out + (size_t)n * D + c) = r;
}

__global__ __launch_bounds__(256, 4) void transform3_kernel(
    float* __restrict__ out, const float* __restrict__ W,
    const float* __restrict__ b, int N)
{
    __shared__ float Ws[D * D];
    __shared__ float hs[16][D + 4];

    const int tid = threadIdx.x;
    for (int i = tid; i < D * D; i += 256) Ws[i] = W[i];

    const int c0 = (tid & 63) * 2;
    const int rb = (tid >> 6) * 4;
    float2 bias; bias.x = b[c0]; bias.y = b[c0 + 1];
    const int lr = tid >> 4;
    const int lc = (tid & 15) * 8;
    __syncthreads();

    for (int n0 = blockIdx.x * 16; n0 < N; n0 += gridDim.x * 16) {
        const int ln = n0 + lr;
        if (ln < N) {
            *(float4*)&hs[lr][lc]     = *(const float4*)(out + (size_t)ln * D + lc);
            *(float4*)&hs[lr][lc + 4] = *(const float4*)(out + (size_t)ln * D + lc + 4);
        } else {
            const float4 z = make_float4(0.f, 0.f, 0.f, 0.f);
            *(float4*)&hs[lr][lc] = z;
            *(float4*)&hs[lr][lc + 4] = z;
        }
        __syncthreads();

        float2 acc0 = bias, acc1 = bias, acc2 = bias, acc3 = bias;
        #pragma unroll 2
        for (int k = 0; k < D; k += 4) {
            const float4 h0 = *(const float4*)&hs[rb + 0][k];
            const float4 h1 = *(const float4*)&hs[rb + 1][k];
            const float4 h2 = *(const float4*)&hs[rb + 2][k];
            const float4 h3 = *(const float4*)&hs[rb + 3][k];
            #pragma unroll
            for (int kk = 0; kk < 4; ++kk) {
                const float2 w = *(const float2*)&Ws[(k + kk) * D + c0];
                const float e0 = (kk == 0) ? h0.x : (kk == 1) ? h0.y : (kk == 2) ? h0.z : h0.w;
                const float e1 = (kk == 0) ? h1.x : (kk == 1) ? h1.y : (kk == 2) ? h1.z : h1.w;
                const float e2 = (kk == 0) ? h2.x : (kk == 1) ? h2.y : (kk == 2) ? h2.z : h2.w;
                const float e3 = (kk == 0) ? h3.x : (kk == 1) ? h3.y : (kk == 2) ? h3.z : h3.w;
                acc0.x = fmaf(e0, w.x, acc0.x); acc0.y = fmaf(e0, w.y, acc0.y);
                acc1.x = fmaf(e1, w.x, acc1.x); acc1.y = fmaf(e1, w.y, acc1.y);
                acc2.x = fmaf(e2, w.x, acc2.x); acc2.y = fmaf(e2, w.y, acc2.y);
                acc3.x = fmaf(e3, w.x, acc3.x); acc3.y = fmaf(e3, w.y, acc3.y);
            }
        }
        __syncthreads();

        const int nb = n0 + rb;
        if (nb + 0 < N) *(float2*)(out + (size_t)(nb + 0) * D + c0) = acc0;
        if (nb + 1 < N) *(float2*)(out + (size_t)(nb + 1) * D + c0) = acc1;
        if (nb + 2 < N) *(float2*)(out + (size_t)(nb + 2) * D + c0) = acc2;
        if (nb + 3 < N) *(float2*)(out + (size_t)(nb + 3) * D + c0) = acc3;
    }
}

// ---------------- atomic fallback ----------------

__global__ __launch_bounds__(256) void scatter_kernel(
    const float* __restrict__ inputs, const int* __restrict__ src,
    const int* __restrict__ dst, float* __restrict__ out, long long total_threads)
{
    long long tid = (long long)blockIdx.x * blockDim.x + threadIdx.x;
    if (tid >= total_threads) return;
    int e = (int)(tid >> 5);
    int lane = (int)(tid & 31);
    const float4 v = *(const float4*)(inputs + (size_t)src[e] * D + lane * 4);
    float* op = out + (size_t)dst[e] * D + lane * 4;
    atomicAdd(op + 0, v.x);
    atomicAdd(op + 1, v.y);
    atomicAdd(op + 2, v.z);
    atomicAdd(op + 3, v.w);
}

__global__ __launch_bounds__(256) void divide_kernel(
    float* __restrict__ out, const float* __restrict__ degree, int N)
{
    long long i = (long long)blockIdx.x * 256 + threadIdx.x;
    if (i < (long long)N * D) out[i] /= degree[i >> 7];
}

extern "C" void kernel_launch(void* const* d_in, const int* in_sizes, int n_in,
                              void* d_out, int out_size, void* d_ws, size_t ws_size,
                              hipStream_t stream) {
    const float* inputs = (const float*)d_in[0];
    const int*   src    = (const int*)d_in[1];
    const int*   dst    = (const int*)d_in[2];
    const float* degree = (const float*)d_in[3];
    const float* W      = (const float*)d_in[4];
    const float* b      = (const float*)d_in[5];
    float* out = (float*)d_out;

    const int E = in_sizes[1];
    const int N = in_sizes[3];
    const int nscan = (N + 255) / 256;

    // ws layout: starts[N] | work[N] | bsum[512] | edge_src[E+N] | (align16) h_bf16[N*D]
    // xin (bf16 copy of inputs) lives in d_out's first 25.6 MB — dead until transform writes.
    const size_t ints_csr  = (size_t)3 * N + 512 + E;
    const size_t h_off     = ((ints_csr * 4) + 15) & ~(size_t)15;
    const size_t needed_full = h_off + (size_t)N * D * 2;
    const size_t needed_csr  = ints_csr * 4;

    if (ws_size >= needed_full && nscan <= 4096) {
        int* starts   = (int*)d_ws;
        int* work     = starts + N;
        int* bsum     = work + N;
        int* edge_src = bsum + 512;
        unsigned short* hbf = (unsigned short*)((char*)d_ws + h_off);
        unsigned short* xin = (unsigned short*)d_out;   // scratch alias, freed by stream order

        const long long total8 = (long long)N * D / 8;
        cast_bf16_kernel<<<(int)((total8 + 255) / 256), 256, 0, stream>>>(inputs, xin, total8);
        scan_partial_kernel<<<nscan, 256, 0, stream>>>(degree, bsum, N);
        scan_offsets_kernel<<<nscan, 256, 0, stream>>>(degree, bsum, starts, work, N);
        bucket_kernel<<<(E + 255) / 256, 256, 0, stream>>>(src, dst, work, edge_src, E);
        aggregate_xbf4_kernel<<<(N + 3) / 4, 256, 0, stream>>>(
            xin, edge_src, starts, work, degree, hbf, N);
        transform_mfma_kernel<<<512, 512, 0, stream>>>(hbf, W, b, out, N);
    } else if (ws_size >= needed_csr && nscan <= 4096) {
        int* starts   = (int*)d_ws;
        int* work     = starts + N;
        int* bsum     = work + N;
        int* edge_src = bsum + 512;

        scan_partial_kernel<<<nscan, 256, 0, stream>>>(degree, bsum, N);
        scan_offsets_kernel<<<nscan, 256, 0, stream>>>(degree, bsum, starts, work, N);
        bucket_kernel<<<(E + 255) / 256, 256, 0, stream>>>(src, dst, work, edge_src, E);
        aggregate_f32_kernel<<<(N + 3) / 4, 256, 0, stream>>>(
            inputs, edge_src, starts, work, degree, out, N);
        transform3_kernel<<<2048, 256, 0, stream>>>(out, W, b, N);
    } else {
        hipMemsetAsync(d_out, 0, (size_t)N * D * sizeof(float), stream);
        const long long total = (long long)E * 32;
        scatter_kernel<<<(int)((total + 255) / 256), 256, 0, stream>>>(inputs, src, dst, out, total);
        divide_kernel<<<(int)(((long long)N * D + 255) / 256), 256, 0, stream>>>(out, degree, N);
        transform3_kernel<<<2048, 256, 0, stream>>>(out, W, b, N);
    }
}

// Round 7
// 110.976 us; speedup vs baseline: 17.0244x; 1.0470x over previous
//
#include <hip/hip_runtime.h>

constexpr int D = 128;

using short8 = __attribute__((ext_vector_type(8))) short;
using f32x4  = __attribute__((ext_vector_type(4))) float;

__device__ inline unsigned short f2bf(float f) {
    unsigned u = __float_as_uint(f);
    u = (u + 0x7FFFu + ((u >> 16) & 1u)) >> 16;   // RN-even
    return (unsigned short)u;
}
__device__ inline unsigned pack2bf(float a, float b) {
    return (unsigned)f2bf(a) | ((unsigned)f2bf(b) << 16);
}

// ---------------- CSR-build (counts derived from degree; no hist) ----------------

__global__ __launch_bounds__(256) void scan_partial_kernel(
    const float* __restrict__ degree, int* __restrict__ bsum, int N)
{
    __shared__ int a[256];
    int i = blockIdx.x * 256 + threadIdx.x;
    a[threadIdx.x] = (i < N) ? (int)degree[i] : 0;
    __syncthreads();
    for (int off = 128; off > 0; off >>= 1) {
        if (threadIdx.x < off) a[threadIdx.x] += a[threadIdx.x + off];
        __syncthreads();
    }
    if (threadIdx.x == 0) bsum[blockIdx.x] = a[0];
}

// offsets with inline prefix over bsum (no separate bsum-scan launch)
__global__ __launch_bounds__(256) void scan_offsets_kernel(
    const float* __restrict__ degree, const int* __restrict__ bsum,
    int* __restrict__ starts, int* __restrict__ work, int N)
{
    __shared__ int a[256], b2[256];
    __shared__ int prefix_s;
    const int t = threadIdx.x;
    const int i = blockIdx.x * 256 + t;

    int p = 0;
    for (int j = t; j < blockIdx.x; j += 256) p += bsum[j];
    a[t] = p;
    __syncthreads();
    for (int off = 128; off > 0; off >>= 1) {
        if (t < off) a[t] += a[t + off];
        __syncthreads();
    }
    if (t == 0) prefix_s = a[0];
    __syncthreads();
    const int prefix = prefix_s;
    __syncthreads();

    const int v = (i < N) ? (int)degree[i] : 0;
    a[t] = v;
    __syncthreads();
    int* cur = a; int* nxt = b2;
    for (int off = 1; off < 256; off <<= 1) {
        int x = cur[t];
        if (t >= off) x += cur[t - off];
        nxt[t] = x;
        __syncthreads();
        int* tmp = cur; cur = nxt; nxt = tmp;
    }
    if (i < N) {
        const int val = prefix + cur[t] - v;   // exclusive
        starts[i] = val;
        work[i]   = val;
    }
}

__global__ __launch_bounds__(256) void bucket_kernel(
    const int* __restrict__ src, const int* __restrict__ dst,
    int* __restrict__ work, int* __restrict__ edge_src, int E)
{
    int e = blockIdx.x * 256 + threadIdx.x;
    if (e < E) {
        int pos = atomicAdd(&work[dst[e]], 1);
        edge_src[pos] = src[e];
    }
}

// ---------------- GEMM first: y = bf16(x) @ bf16(W), y bf16, NO bias ----------------
// 512 thr = 8 waves, 64-row tile/iter. A read fp32 from x, cast in-reg.
__global__ __launch_bounds__(512) void gemm_xw_kernel(
    const float* __restrict__ x, const float* __restrict__ W,
    unsigned short* __restrict__ y, int N)
{
    __shared__ float Wlds[D * D];        // 64 KB, frag-build only
    const int tid = threadIdx.x;
    for (int i = tid; i < D * D / 4; i += 512)
        ((float4*)Wlds)[i] = ((const float4*)W)[i];
    __syncthreads();

    const int l    = tid & 63;
    const int wave = tid >> 6;
    const int wr   = wave >> 1;          // 0..3 row sub-tile
    const int wc   = wave & 1;           // 0..1 col half
    const int lcol = l & 15;
    const int lk   = (l >> 4) * 8;

    short8 Bf[4][4];
    #pragma unroll
    for (int c = 0; c < 4; ++c) {
        const int col = wc * 64 + c * 16 + lcol;
        #pragma unroll
        for (int ks = 0; ks < 4; ++ks) {
            #pragma unroll
            for (int j = 0; j < 8; ++j)
                Bf[c][ks][j] = (short)f2bf(Wlds[(ks * 32 + lk + j) * D + col]);
        }
    }

    for (int r0 = blockIdx.x * 64 + wr * 16; r0 < N; r0 += gridDim.x * 64) {
        const int arow = r0 + lcol;
        short8 Af[4];
        if (arow < N) {
            #pragma unroll
            for (int ks = 0; ks < 4; ++ks) {
                const float4 a0 = *(const float4*)(x + (size_t)arow * D + ks * 32 + lk);
                const float4 a1 = *(const float4*)(x + (size_t)arow * D + ks * 32 + lk + 4);
                Af[ks][0] = (short)f2bf(a0.x); Af[ks][1] = (short)f2bf(a0.y);
                Af[ks][2] = (short)f2bf(a0.z); Af[ks][3] = (short)f2bf(a0.w);
                Af[ks][4] = (short)f2bf(a1.x); Af[ks][5] = (short)f2bf(a1.y);
                Af[ks][6] = (short)f2bf(a1.z); Af[ks][7] = (short)f2bf(a1.w);
            }
        } else {
            #pragma unroll
            for (int ks = 0; ks < 4; ++ks) Af[ks] = short8{0,0,0,0,0,0,0,0};
        }

        #pragma unroll
        for (int c = 0; c < 4; ++c) {
            f32x4 acc = {0.f, 0.f, 0.f, 0.f};
            #pragma unroll
            for (int ks = 0; ks < 4; ++ks)
                acc = __builtin_amdgcn_mfma_f32_16x16x32_bf16(Af[ks], Bf[c][ks], acc, 0, 0, 0);
            const int col = wc * 64 + c * 16 + lcol;
            #pragma unroll
            for (int q = 0; q < 4; ++q) {
                const int row = r0 + (l >> 4) * 4 + q;
                if (row < N) y[(size_t)row * D + col] = f2bf(acc[q]);
            }
        }
    }
}

// ---------------- aggregate: out[n] = (sum y[s]) / deg[n] + b ----------------
// npw nodes per wave (long-lived waves). 16 lanes/row (uint4 = 8 bf16),
// 4 edge slots/wave-load. Cross-slot reduce shfl_xor(16,32); fused bias.
__global__ __launch_bounds__(256) void aggregate_y_kernel(
    const unsigned short* __restrict__ y, const int* __restrict__ edge_src,
    const int* __restrict__ starts, const int* __restrict__ work,
    const float* __restrict__ degree, const float* __restrict__ bias,
    float* __restrict__ out, int N, int npw)
{
    const int wid  = threadIdx.x >> 6;
    const int lane = threadIdx.x & 63;
    const int g = lane >> 4;            // edge slot 0..3
    const int t = lane & 15;            // col group: cols t*8 .. t*8+7
    const size_t coff = (size_t)t * 8;

    const long long w = (long long)blockIdx.x * 4 + wid;
    int n = (int)(w * npw);
    if (n >= N) return;
    const int nend = (n + npw < N) ? n + npw : N;

    // store lanes: g==0 writes cols coff..+3, g==1 writes coff+4..+7
    const float4 bq = *(const float4*)(bias + coff + (g & 1) * 4);

    for (; n < nend; ++n) {
        const int beg = starts[n];
        const int end = work[n];

        float ax[8];
        #pragma unroll
        for (int k = 0; k < 8; ++k) ax[k] = 0.f;

        #pragma unroll 2
        for (int i = beg; i < end; i += 4) {
            const int ii = i + g;
            if (ii < end) {
                const int s = edge_src[ii];
                const uint4 v = *(const uint4*)(y + (size_t)s * D + coff);
                ax[0] += __uint_as_float(v.x << 16);
                ax[1] += __uint_as_float(v.x & 0xFFFF0000u);
                ax[2] += __uint_as_float(v.y << 16);
                ax[3] += __uint_as_float(v.y & 0xFFFF0000u);
                ax[4] += __uint_as_float(v.z << 16);
                ax[5] += __uint_as_float(v.z & 0xFFFF0000u);
                ax[6] += __uint_as_float(v.w << 16);
                ax[7] += __uint_as_float(v.w & 0xFFFF0000u);
            }
        }

        #pragma unroll
        for (int k = 0; k < 8; ++k) {
            ax[k] += __shfl_xor(ax[k], 16, 64);
            ax[k] += __shfl_xor(ax[k], 32, 64);
        }

        if (g < 2) {
            const float invd = 1.0f / degree[n];
            const int kb = (g & 1) * 4;
            float4 o;
            o.x = ax[kb + 0] * invd + bq.x;
            o.y = ax[kb + 1] * invd + bq.y;
            o.z = ax[kb + 2] * invd + bq.z;
            o.w = ax[kb + 3] * invd + bq.w;
            *(float4*)(out + (size_t)n * D + coff + kb) = o;
        }
    }
}

// ---------------- mid path (fp32 h in d_out) ----------------

__global__ __launch_bounds__(256) void aggregate_f32_kernel(
    const float* __restrict__ inputs, const int* __restrict__ edge_src,
    const int* __restrict__ starts, const int* __restrict__ work,
    const float* __restrict__ degree, float* __restrict__ out, int N)
{
    const int wid = threadIdx.x >> 6;
    const int lane = threadIdx.x & 63;
    const int n = blockIdx.x * 4 + wid;
    if (n >= N) return;
    const int beg = starts[n];
    const int end = work[n];
    const int c = lane * 2;
    float ax = 0.f, ay = 0.f;
    for (int i = beg; i < end; ++i) {
        const float2 v = *(const float2*)(inputs + (size_t)edge_src[i] * D + c);
        ax += v.x;
        ay += v.y;
    }
    const float invd = 1.0f / degree[n];
    float2 r; r.x = ax * invd; r.y = ay * invd;
    *(float2*)(out + (size_t)n * D + c) = r;
}

__global__ __launch_bounds__(256, 4) void transform3_kernel(
    float* __restrict__ out, const float* __restrict__ W,
    const float* __restrict__ b, int N)
{
    __shared__ float Ws[D * D];
    __shared__ float hs[16][D + 4];

    const int tid = threadIdx.x;
    for (int i = tid; i < D * D; i += 256) Ws[i] = W[i];

    const int c0 = (tid & 63) * 2;
    const int rb = (tid >> 6) * 4;
    float2 bias; bias.x = b[c0]; bias.y = b[c0 + 1];
    const int lr = tid >> 4;
    const int lc = (tid & 15) * 8;
    __syncthreads();

    for (int n0 = blockIdx.x * 16; n0 < N; n0 += gridDim.x * 16) {
        const int ln = n0 + lr;
        if (ln < N) {
            *(float4*)&hs[lr][lc]     = *(const float4*)(out + (size_t)ln * D + lc);
            *(float4*)&hs[lr][lc + 4] = *(const float4*)(out + (size_t)ln * D + lc + 4);
        } else {
            const float4 z = make_float4(0.f, 0.f, 0.f, 0.f);
            *(float4*)&hs[lr][lc] = z;
            *(float4*)&hs[lr][lc + 4] = z;
        }
        __syncthreads();

        float2 acc0 = bias, acc1 = bias, acc2 = bias, acc3 = bias;
        #pragma unroll 2
        for (int k = 0; k < D; k += 4) {
            const float4 h0 = *(const float4*)&hs[rb + 0][k];
            const float4 h1 = *(const float4*)&hs[rb + 1][k];
            const float4 h2 = *(const float4*)&hs[rb + 2][k];
            const float4 h3 = *(const float4*)&hs[rb + 3][k];
            #pragma unroll
            for (int kk = 0; kk < 4; ++kk) {
                const float2 w = *(const float2*)&Ws[(k + kk) * D + c0];
                const float e0 = (kk == 0) ? h0.x : (kk == 1) ? h0.y : (kk == 2) ? h0.z : h0.w;
                const float e1 = (kk == 0) ? h1.x : (kk == 1) ? h1.y : (kk == 2) ? h1.z : h1.w;
                const float e2 = (kk == 0) ? h2.x : (kk == 1) ? h2.y : (kk == 2) ? h2.z : h2.w;
                const float e3 = (kk == 0) ? h3.x : (kk == 1) ? h3.y : (kk == 2) ? h3.z : h3.w;
                acc0.x = fmaf(e0, w.x, acc0.x); acc0.y = fmaf(e0, w.y, acc0.y);
                acc1.x = fmaf(e1, w.x, acc1.x); acc1.y = fmaf(e1, w.y, acc1.y);
                acc2.x = fmaf(e2, w.x, acc2.x); acc2.y = fmaf(e2, w.y, acc2.y);
                acc3.x = fmaf(e3, w.x, acc3.x); acc3.y = fmaf(e3, w.y, acc3.y);
            }
        }
        __syncthreads();

        const int nb = n0 + rb;
        if (nb + 0 < N) *(float2*)(out + (size_t)(nb + 0) * D + c0) = acc0;
        if (nb + 1 < N) *(float2*)(out + (size_t)(nb + 1) * D + c0) = acc1;
        if (nb + 2 < N) *(float2*)(out + (size_t)(nb + 2) * D + c0) = acc2;
        if (nb + 3 < N) *(float2*)(out + (size_t)(nb + 3) * D + c0) = acc3;
    }
}

// ---------------- atomic fallback ----------------

__global__ __launch_bounds__(256) void scatter_kernel(
    const float* __restrict__ inputs, const int* __restrict__ src,
    const int* __restrict__ dst, float* __restrict__ out, long long total_threads)
{
    long long tid = (long long)blockIdx.x * blockDim.x + threadIdx.x;
    if (tid >= total_threads) return;
    int e = (int)(tid >> 5);
    int lane = (int)(tid & 31);
    const float4 v = *(const float4*)(inputs + (size_t)src[e] * D + lane * 4);
    float* op = out + (size_t)dst[e] * D + lane * 4;
    atomicAdd(op + 0, v.x);
    atomicAdd(op + 1, v.y);
    atomicAdd(op + 2, v.z);
    atomicAdd(op + 3, v.w);
}

__global__ __launch_bounds__(256) void divide_kernel(
    float* __restrict__ out, const float* __restrict__ degree, int N)
{
    long long i = (long long)blockIdx.x * 256 + threadIdx.x;
    if (i < (long long)N * D) out[i] /= degree[i >> 7];
}

extern "C" void kernel_launch(void* const* d_in, const int* in_sizes, int n_in,
                              void* d_out, int out_size, void* d_ws, size_t ws_size,
                              hipStream_t stream) {
    const float* inputs = (const float*)d_in[0];
    const int*   src    = (const int*)d_in[1];
    const int*   dst    = (const int*)d_in[2];
    const float* degree = (const float*)d_in[3];
    const float* W      = (const float*)d_in[4];
    const float* b      = (const float*)d_in[5];
    float* out = (float*)d_out;

    const int E = in_sizes[1];
    const int N = in_sizes[3];
    const int nscan = (N + 255) / 256;

    // ws layout: starts[N] | work[N] | bsum[512] | edge_src[E+N] | (align16) y_bf16[N*D]
    const size_t ints_csr  = (size_t)3 * N + 512 + E;
    const size_t y_off     = ((ints_csr * 4) + 15) & ~(size_t)15;
    const size_t needed_full = y_off + (size_t)N * D * 2;
    const size_t needed_csr  = ints_csr * 4;

    if (ws_size >= needed_full && nscan <= 4096) {
        int* starts   = (int*)d_ws;
        int* work     = starts + N;
        int* bsum     = work + N;
        int* edge_src = bsum + 512;
        unsigned short* ybf = (unsigned short*)((char*)d_ws + y_off);

        scan_partial_kernel<<<nscan, 256, 0, stream>>>(degree, bsum, N);
        scan_offsets_kernel<<<nscan, 256, 0, stream>>>(degree, bsum, starts, work, N);
        bucket_kernel<<<(E + 255) / 256, 256, 0, stream>>>(src, dst, work, edge_src, E);
        gemm_xw_kernel<<<512, 512, 0, stream>>>(inputs, W, ybf, N);

        const int npw = (N + 8191) / 8192;                 // nodes per wave (~13)
        const int nwaves = (N + npw - 1) / npw;
        aggregate_y_kernel<<<(nwaves + 3) / 4, 256, 0, stream>>>(
            ybf, edge_src, starts, work, degree, b, out, N, npw);
    } else if (ws_size >= needed_csr && nscan <= 4096) {
        int* starts   = (int*)d_ws;
        int* work     = starts + N;
        int* bsum     = work + N;
        int* edge_src = bsum + 512;

        scan_partial_kernel<<<nscan, 256, 0, stream>>>(degree, bsum, N);
        scan_offsets_kernel<<<nscan, 256, 0, stream>>>(degree, bsum, starts, work, N);
        bucket_kernel<<<(E + 255) / 256, 256, 0, stream>>>(src, dst, work, edge_src, E);
        aggregate_f32_kernel<<<(N + 3) / 4, 256, 0, stream>>>(
            inputs, edge_src, starts, work, degree, out, N);
        transform3_kernel<<<2048, 256, 0, stream>>>(out, W, b, N);
    } else {
        hipMemsetAsync(d_out, 0, (size_t)N * D * sizeof(float), stream);
        const long long total = (long long)E * 32;
        scatter_kernel<<<(int)((total + 255) / 256), 256, 0, stream>>>(inputs, src, dst, out, total);
        divide_kernel<<<(int)(((long long)N * D + 255) / 256), 256, 0, stream>>>(out, degree, N);
        transform3_kernel<<<2048, 256, 0, stream>>>(out, W, b, N);
    }
}